// Round 1
// baseline (151.561 us; speedup 1.0000x reference)
//
#include <hip/hip_runtime.h>
#include <math.h>

// Problem constants
#define B_   8
#define L_   256
#define C_   512
#define OUT_ 512

typedef _Float16 half8 __attribute__((ext_vector_type(8)));
typedef _Float16 half4 __attribute__((ext_vector_type(4)));
typedef float    f32x4 __attribute__((ext_vector_type(4)));
typedef float    f32x2 __attribute__((ext_vector_type(2)));

// ---------------------------------------------------------------------------
// Kernel 1: MFMA relu-GEMM projections (f32 in, f16 frags, f32 acc, f16 out).
//   Y[m][n] = sum_k relu(X[m][k]) * W[k][n] + bias[n],  W raw f32 [k][n].
// 64x64 tile, KT=32, dbuf, 1 barrier/step. grid (8,32,2), 256 thr. (unchanged)
// ---------------------------------------------------------------------------
__global__ __launch_bounds__(256)
void proj_mfma_kernel(const float* __restrict__ xt, const float* __restrict__ Wp,
                      const float* __restrict__ bp,
                      const float* __restrict__ xd, const float* __restrict__ Wc,
                      const float* __restrict__ bc,
                      _Float16* __restrict__ pt, _Float16* __restrict__ pc)
{
    const int which = blockIdx.z;
    const float* __restrict__ X    = which ? xd : xt;
    const float* __restrict__ W    = which ? Wc : Wp;
    const float* __restrict__ bias = which ? bc : bp;
    _Float16*    __restrict__ Y    = which ? pc : pt;

    __shared__ _Float16 Ah[2][64][40];   // [buf][m][k]
    __shared__ _Float16 Bh[2][64][40];   // [buf][n][k]
    __shared__ _Float16 Ot[64][72];

    const int tid = threadIdx.x;
    const int m0 = blockIdx.y << 6, n0 = blockIdx.x << 6;
    const int lane = tid & 63, wv = tid >> 6;
    const int l15 = lane & 15, quad = lane >> 4;

    const int srow = tid >> 2, sch = (tid & 3) << 3;
    const float* Ag = X + (size_t)(m0 + srow) * C_ + sch;
    const int nl = tid & 63, kseg = tid >> 6;
    const float* Bg = W + (size_t)(kseg << 3) * C_ + n0 + nl;

    float4 a0 = *(const float4*)(Ag);
    float4 a1 = *(const float4*)(Ag + 4);
    float wr[8];
    #pragma unroll
    for (int r = 0; r < 8; ++r) wr[r] = Bg[(size_t)r * C_];

    {
        half8 av;
        av[0] = (_Float16)fmaxf(a0.x, 0.f); av[1] = (_Float16)fmaxf(a0.y, 0.f);
        av[2] = (_Float16)fmaxf(a0.z, 0.f); av[3] = (_Float16)fmaxf(a0.w, 0.f);
        av[4] = (_Float16)fmaxf(a1.x, 0.f); av[5] = (_Float16)fmaxf(a1.y, 0.f);
        av[6] = (_Float16)fmaxf(a1.z, 0.f); av[7] = (_Float16)fmaxf(a1.w, 0.f);
        *(half8*)&Ah[0][srow][sch] = av;
        half8 bv;
        #pragma unroll
        for (int r = 0; r < 8; ++r) bv[r] = (_Float16)wr[r];
        *(half8*)&Bh[0][nl][kseg << 3] = bv;
    }

    f32x4 acc[4] = {};
    for (int ks = 0; ks < 16; ++ks) {
        const int cur = ks & 1;
        if (ks < 15) {
            Ag += 32;
            Bg += 32 * C_;
            a0 = *(const float4*)(Ag);
            a1 = *(const float4*)(Ag + 4);
            #pragma unroll
            for (int r = 0; r < 8; ++r) wr[r] = Bg[(size_t)r * C_];
        }
        __syncthreads();
        half8 af = *(const half8*)&Ah[cur][(wv << 4) + l15][quad << 3];
        #pragma unroll
        for (int nb = 0; nb < 4; ++nb) {
            half8 bf = *(const half8*)&Bh[cur][(nb << 4) + l15][quad << 3];
            acc[nb] = __builtin_amdgcn_mfma_f32_16x16x32_f16(af, bf, acc[nb], 0, 0, 0);
        }
        if (ks < 15) {
            half8 av;
            av[0] = (_Float16)fmaxf(a0.x, 0.f); av[1] = (_Float16)fmaxf(a0.y, 0.f);
            av[2] = (_Float16)fmaxf(a0.z, 0.f); av[3] = (_Float16)fmaxf(a0.w, 0.f);
            av[4] = (_Float16)fmaxf(a1.x, 0.f); av[5] = (_Float16)fmaxf(a1.y, 0.f);
            av[6] = (_Float16)fmaxf(a1.z, 0.f); av[7] = (_Float16)fmaxf(a1.w, 0.f);
            *(half8*)&Ah[cur ^ 1][srow][sch] = av;
            half8 bv;
            #pragma unroll
            for (int r = 0; r < 8; ++r) bv[r] = (_Float16)wr[r];
            *(half8*)&Bh[cur ^ 1][nl][kseg << 3] = bv;
        }
    }

    __syncthreads();
    #pragma unroll
    for (int nb = 0; nb < 4; ++nb) {
        const float bz = bias[n0 + (nb << 4) + l15];
        #pragma unroll
        for (int r = 0; r < 4; ++r)
            Ot[(wv << 4) + (quad << 2) + r][(nb << 4) + l15] = (_Float16)(acc[nb][r] + bz);
    }
    __syncthreads();
    const int erow = tid >> 3, ech = (tid & 7) << 3;
    #pragma unroll
    for (int h = 0; h < 64; h += 32)
        *(half8*)&Y[(size_t)(m0 + erow + h) * C_ + n0 + ech] = *(const half8*)&Ot[erow + h][ech];
}

// ---------------------------------------------------------------------------
__device__ __forceinline__ float sigmoid_fast(float z) {
    float e = __builtin_amdgcn_exp2f(-1.4426950408889634f * z);
    return __builtin_amdgcn_rcpf(e + 1.0f);
}

// ---------------------------------------------------------------------------
// Kernel 2a (NEW): sigmoid scores via MFMA, fragments direct from global.
// Per block: 32x32 (i,j) tile for one b; 4 waves = 4 16x16 quadrants.
// No LDS staging, no K-loop barriers (pt/pc are L2-resident; per-quad frag
// loads are 64B-coalesced across the wave). Writes w (f32) + per-tile sums.
// grid (8,8,8), 256 thr.
// ---------------------------------------------------------------------------
__global__ __launch_bounds__(256)
void scores_kernel(const _Float16* __restrict__ pt, const _Float16* __restrict__ pc,
                   float* __restrict__ w, float* __restrict__ sums_part)
{
    const int bx = blockIdx.x, by = blockIdx.y, b = blockIdx.z;
    const int i0 = bx << 5, j0 = by << 5;
    const int tid = threadIdx.x;
    const int lane = tid & 63, wv = tid >> 6;
    const int l15 = lane & 15, quad = lane >> 4;
    const int mq = wv >> 1, nq = wv & 1;

    __shared__ float wred[4];

    // A-frag: lane&15 = row, (lane>>4)*8 = k-offset inside the 32-k step.
    const _Float16* __restrict__ Ap =
        pt + (size_t)(b * L_ + i0 + mq * 16 + l15) * C_ + (quad << 3);
    const _Float16* __restrict__ Bp =
        pc + (size_t)(b * L_ + j0 + nq * 16 + l15) * C_ + (quad << 3);

    f32x4 acc = {};
    #pragma unroll
    for (int ks = 0; ks < 16; ++ks) {
        half8 af = *(const half8*)(Ap + (ks << 5));
        half8 bf = *(const half8*)(Bp + (ks << 5));
        acc = __builtin_amdgcn_mfma_f32_16x16x32_f16(af, bf, acc, 0, 0, 0);
    }

    // C/D layout: col = lane&15 (j), row = quad*4 + r (i).
    float4 sg;
    sg.x = sigmoid_fast(acc[0]);
    sg.y = sigmoid_fast(acc[1]);
    sg.z = sigmoid_fast(acc[2]);
    sg.w = sigmoid_fast(acc[3]);

    float* __restrict__ wp =
        w + (size_t)(b * L_ + i0 + mq * 16 + (quad << 2)) * L_ + j0 + nq * 16 + l15;
    wp[0 * L_] = sg.x;
    wp[1 * L_] = sg.y;
    wp[2 * L_] = sg.z;
    wp[3 * L_] = sg.w;

    float lsum = (sg.x + sg.y) + (sg.z + sg.w);
    #pragma unroll
    for (int off = 32; off; off >>= 1) lsum += __shfl_xor(lsum, off);
    if (lane == 0) wred[wv] = lsum;
    __syncthreads();
    if (tid == 0)
        sums_part[(b << 6) | (bx << 3) | by] = (wred[0] + wred[1]) + (wred[2] + wred[3]);
}

// ---------------------------------------------------------------------------
// Kernel 2b (NEW): weighted tanh-r accumulation, pure VALU, high occupancy.
//   partial[b][p][c] = sum_{i,j in tile} w[i][j] * r(xd[i,c]*xt[j,c]),
//   r = 1/(1+exp2(2*log2e*x));  tanh = 1-2r recovered in finalize.
// 16x16 (i,j) tile -> grid (16,16,8) = 2048 blocks x 512 thr (thread = c).
// Per-thread state: 8 packed xd pairs + 2 pk accumulators (small -> <=64 VGPR
// -> 4 blocks/CU = 32 waves/CU). w tile transposed into 1 KB LDS, broadcast
// float4 reads (conflict-free). xt re-read per jj from L2.
// ---------------------------------------------------------------------------
__global__ __launch_bounds__(512, 8)
void tanh_cp_kernel(const float* __restrict__ w, const float* __restrict__ xd,
                    const float* __restrict__ xt, float* __restrict__ partials)
{
    const int bx = blockIdx.x, by = blockIdx.y, b = blockIdx.z;
    const int i0 = bx << 4, j0 = by << 4;
    const int tid = threadIdx.x;

    __shared__ float ws_[16][20];     // [j][i], transposed w tile

    if (tid < 64) {
        const int ir = tid >> 2, j4 = (tid & 3) << 2;
        const float4 v = *(const float4*)(w + (size_t)(b * L_ + i0 + ir) * L_ + j0 + j4);
        ws_[j4 + 0][ir] = v.x;
        ws_[j4 + 1][ir] = v.y;
        ws_[j4 + 2][ir] = v.z;
        ws_[j4 + 3][ir] = v.w;
    }

    const int c = tid;
    const float* __restrict__ xdb = xd + (size_t)(b * L_ + i0) * C_ + c;
    const float* __restrict__ xtb = xt + (size_t)(b * L_ + j0) * C_ + c;

    f32x2 xds2[8];                    // 16 xd rows, packed in pairs
    #pragma unroll
    for (int i = 0; i < 8; ++i) {
        xds2[i].x = xdb[(size_t)(2 * i) * C_];
        xds2[i].y = xdb[(size_t)(2 * i + 1) * C_];
    }

    __syncthreads();

    f32x2 acc01 = {0.f, 0.f}, acc23 = {0.f, 0.f};
    #pragma unroll
    for (int jj = 0; jj < 16; ++jj) {
        const float xv = xtb[(size_t)jj * C_] * 2.8853900817779268f;   // 2*log2(e)
        #pragma unroll
        for (int i = 0; i < 16; i += 4) {
            const float4 w4 = *(const float4*)&ws_[jj][i];             // uniform broadcast
            // pair (i, i+1)
            f32x2 x01 = xds2[i >> 1] * xv;                             // v_pk_mul
            f32x2 e01 = { __builtin_amdgcn_exp2f(x01.x), __builtin_amdgcn_exp2f(x01.y) };
            f32x2 q01 = e01 + 1.0f;                                    // v_pk_add
            float rp01 = __builtin_amdgcn_rcpf(q01.x * q01.y);
            f32x2 r01 = rp01 * __builtin_shufflevector(q01, q01, 1, 0);
            f32x2 w01 = { w4.x, w4.y };
            acc01 = w01 * r01 + acc01;                                 // v_pk_fma
            // pair (i+2, i+3)
            f32x2 x23 = xds2[(i >> 1) + 1] * xv;
            f32x2 e23 = { __builtin_amdgcn_exp2f(x23.x), __builtin_amdgcn_exp2f(x23.y) };
            f32x2 q23 = e23 + 1.0f;
            float rp23 = __builtin_amdgcn_rcpf(q23.x * q23.y);
            f32x2 r23 = rp23 * __builtin_shufflevector(q23, q23, 1, 0);
            f32x2 w23 = { w4.z, w4.w };
            acc23 = w23 * r23 + acc23;
        }
    }
    const int p = (bx << 4) | by;     // 0..255
    partials[(size_t)((b << 8) | p) * C_ + c] =
        (acc01.x + acc01.y) + (acc23.x + acc23.y);
}

// ---------------------------------------------------------------------------
// Kernel 3: S = sum(scores); cp[b,c] = 1 - 2*(sum_p partial)/S; out = cp@Wf+bf
// grid (8,8), 512 thr.  (p count now 256)
// ---------------------------------------------------------------------------
__global__ __launch_bounds__(512)
void finalize_kernel(const float* __restrict__ partials, const float* __restrict__ sums_part,
                     const float* __restrict__ Wf, const float* __restrict__ bfv,
                     float* __restrict__ out)
{
    const int b = blockIdx.y;
    const int t = threadIdx.x;
    __shared__ float cp[C_];
    __shared__ float red[512];
    __shared__ float sumsh;

    red[t] = (t < 64) ? sums_part[(b << 6) | t] : 0.f;

    float s = 0.f;
    #pragma unroll 8
    for (int p = 0; p < 256; ++p)
        s += partials[(size_t)((b << 8) | p) * C_ + t];

    __syncthreads();
    for (int st = 256; st > 0; st >>= 1) {
        if (t < st) red[t] += red[t + st];
        __syncthreads();
    }
    if (t == 0) sumsh = red[0];
    __syncthreads();

    cp[t] = 1.0f - 2.0f * s / sumsh;
    __syncthreads();

    const int o  = ((int)blockIdx.x << 6) | (t & 63);
    const int c0 = (t >> 6) << 6;
    float acc = 0.f;
    #pragma unroll 8
    for (int i = 0; i < 64; ++i) {
        const int cc = c0 + i;
        acc = fmaf(cp[cc], Wf[(size_t)cc * OUT_ + o], acc);
    }
    red[t] = acc;
    __syncthreads();
    if (t < 64) {
        float a = 0.f;
        #pragma unroll
        for (int g = 0; g < 8; ++g) a += red[(g << 6) | t];
        out[(size_t)b * OUT_ + o] = a + bfv[o];
    }
}

// ---------------------------------------------------------------------------
extern "C" void kernel_launch(void* const* d_in, const int* in_sizes, int n_in,
                              void* d_out, int out_size, void* d_ws, size_t ws_size,
                              hipStream_t stream)
{
    const float* xd = (const float*)d_in[0];
    const float* xt = (const float*)d_in[1];
    const float* Wc = (const float*)d_in[2];
    const float* bc = (const float*)d_in[3];
    const float* Wp = (const float*)d_in[4];
    const float* bp = (const float*)d_in[5];
    const float* Wf = (const float*)d_in[6];
    const float* bf = (const float*)d_in[7];
    float* out = (float*)d_out;

    // workspace (~10 MB)
    _Float16* pt = (_Float16*)d_ws;                  // 2 MB
    _Float16* pc = pt + 1048576;                     // 2 MB
    float* w         = (float*)(pc + 1048576);       // 8*256*256 f = 2 MB
    float* partials  = w + 524288;                   // 8*256*512 f = 4 MB
    float* sums_part = partials + 1048576;           // 512 f

    proj_mfma_kernel<<<dim3(8, 32, 2), 256, 0, stream>>>(xt, Wp, bp, xd, Wc, bc, pt, pc);
    scores_kernel<<<dim3(8, 8, 8), 256, 0, stream>>>(pt, pc, w, sums_part);
    tanh_cp_kernel<<<dim3(16, 16, 8), 512, 0, stream>>>(w, xd, xt, partials);
    finalize_kernel<<<dim3(8, 8), 512, 0, stream>>>(partials, sums_part, Wf, bf, out);
}